// Round 14
// baseline (85.109 us; speedup 1.0000x reference)
//
#include <hip/hip_runtime.h>
#include <math.h>

#define T 34
#define V 14
#define NT 256
#define NBLK 1088
#define NWAVES 4352            // NBLK*4 = 17*256 -> tile stride preserves per-lane t-invariance
#define NPAIRS 4               // 8 tiles/wave as 4 pairs
#define LIM (65536 * 34)
#define GS 36                  // padded row stride (16B-aligned rows)

typedef float f32x4 __attribute__((ext_vector_type(4)));

__attribute__((amdgpu_waves_per_eu(4, 4)))
__global__ __launch_bounds__(NT) void micro_fused(
    const int* __restrict__ idx, float* __restrict__ out,
    const float* __restrict__ p_tokA, const float* __restrict__ p_tokStart,
    const float* __restrict__ p_tokStride, const float* __restrict__ p_spAmp,
    const float* __restrict__ p_spPhase, const float* __restrict__ p_spSlope,
    const float* __restrict__ p_spOffset, const float* __restrict__ norm_w,
    const float* __restrict__ q_w, const float* __restrict__ q_phase,
    const float* __restrict__ out_A, const float* __restrict__ out_B,
    const float* __restrict__ fc1_w, const float* __restrict__ fc2_w,
    const float* __restrict__ head_w)
{
    __shared__ float G_lds[V * GS];        // 2016 B, padded rows
    __shared__ float TE_lds[V * 2];        // 112 B
    __shared__ float POS_lds[T * 3];       // 408 B
    __shared__ float gbW[4][2][2][112];    // per-wave dbuf g staging, 16B-aligned rows (14.3 KB)
    __shared__ float stageAll[4 * 896];    // single logit stage per wave (14.3 KB)
    // total ~31.2 KB -> 4 blocks/CU

    const int tid = threadIdx.x;
    const int w = tid >> 6, lane = tid & 63;
    const int wid = blockIdx.x * 4 + w;

    float* sA = stageAll;            // raw scores A[34][35] during setup
    float* sK = stageAll + 1200;     // K[34][5]
    float* sQ = stageAll + 1370;     // Q[34][5]

    // ---------- setup phase 1: TE, POS, K, Q (parallel) ----------
    if (tid < V) {
        float ang = p_tokStart[0] + (float)tid * p_tokStride[0];
        TE_lds[2 * tid]     = p_tokA[0] * cosf(ang);
        TE_lds[2 * tid + 1] = p_tokA[0] * sinf(ang);
    }
    if (tid < T) {
        float th = (float)tid * 0.62831853071795864769f + p_spPhase[0]; // 2*pi/10
        float p0 = p_spAmp[0] * cosf(th), p1 = p_spAmp[0] * sinf(th);
        float p2 = p_spSlope[0] * (float)tid + p_spOffset[0];
        POS_lds[3 * tid] = p0; POS_lds[3 * tid + 1] = p1; POS_lds[3 * tid + 2] = p2;
        float kk[5];
        #pragma unroll
        for (int i = 0; i < 5; ++i)
            kk[i] = p0 * q_w[3 * i] + p1 * q_w[3 * i + 1] + p2 * q_w[3 * i + 2];
        float cc = cosf(q_phase[0]), ss = sinf(q_phase[0]);
        #pragma unroll
        for (int i = 0; i < 5; ++i) sK[tid * 5 + i] = kk[i];
        sQ[tid * 5 + 0] = cc * kk[0] - ss * kk[1];
        sQ[tid * 5 + 1] = ss * kk[0] + cc * kk[1];
        sQ[tid * 5 + 2] = kk[2]; sQ[tid * 5 + 3] = kk[3]; sQ[tid * 5 + 4] = kk[4];
    }
    __syncthreads();

    // ---------- setup phase 2: raw scores (0 above diag) + padded G table ----------
    for (int e = tid; e < T * T; e += NT) {
        unsigned tt = (unsigned)e / (unsigned)T;
        unsigned s  = (unsigned)e - tt * T;
        float d = 0.f;
        #pragma unroll
        for (int i = 0; i < 5; ++i) d += sQ[tt * 5 + i] * sK[s * 5 + i];
        sA[tt * 35 + s] = (s <= tt) ? d * 0.44721359549995793928f : 0.f;
    }
    for (int e = tid; e < V * GS; e += NT) {
        int v = e / GS, s = e - v * GS;
        float g = 0.f;
        if (s < T) {
            float x0 = TE_lds[2*v], x1 = TE_lds[2*v+1];
            float x2 = POS_lds[3*s], x3 = POS_lds[3*s+1], x4 = POS_lds[3*s+2];
            float ms = (x0*x0 + x1*x1 + x2*x2 + x3*x3 + x4*x4) * 0.2f;
            float r = rsqrtf(ms + 1e-5f);
            g = (x0 * norm_w[0] * out_A[0] + x1 * norm_w[1] * out_A[1]
               + x2 * norm_w[2] * out_A[2] + x3 * norm_w[3] * out_A[3]
               + x4 * norm_w[4] * out_A[4]) * r;
        }
        G_lds[e] = g;
    }
    __syncthreads();

    // ---------- per-lane invariants: load raw score row, softmax in registers ----------
    const int t = (wid * 64 + lane) % T;   // invariant across this wave's tiles
    float A[T];
    #pragma unroll
    for (int s = 0; s < T; ++s) A[s] = sA[t * 35 + s];
    {
        float mx = -1e30f;
        #pragma unroll
        for (int s = 0; s < T; ++s) if (s <= t) mx = fmaxf(mx, A[s]);
        float sum = 0.f;
        #pragma unroll
        for (int s = 0; s < T; ++s) {
            float e2 = (s <= t) ? expf(A[s] - mx) : 0.f;
            A[s] = e2;
            sum += e2;
        }
        float inv = 1.f / sum;
        #pragma unroll
        for (int s = 0; s < T; ++s) A[s] *= inv;
    }
    const float ps0 = POS_lds[3*t], ps1 = POS_lds[3*t+1], ps2 = POS_lds[3*t+2];
    float te0[V], te1[V];
    #pragma unroll
    for (int v = 0; v < V; ++v) { te0[v] = TE_lds[2*v]; te1[v] = TE_lds[2*v+1]; }
    __syncthreads();   // last barrier: stageAll now reusable as logit stage

    // uniform weights: literal-indexed -> scalar loads / SGPRs
    const float nw0 = norm_w[0], nw1 = norm_w[1], nw2 = norm_w[2], nw3 = norm_w[3], nw4 = norm_w[4];
    const float oB0 = out_B[0], oB1 = out_B[1], oB2 = out_B[2], oB3 = out_B[3], oB4 = out_B[4];
    float w1[2][5], hw[2][5], w20[5], w21[5];
    #pragma unroll
    for (int j = 0; j < 2; ++j)
        #pragma unroll
        for (int d = 0; d < 5; ++d) { w1[j][d] = fc1_w[j*5+d]; hw[j][d] = head_w[j*5+d]; }
    #pragma unroll
    for (int d = 0; d < 5; ++d) { w20[d] = fc2_w[2*d]; w21[d] = fc2_w[2*d+1]; }

    // staging-lane invariants (padded-row destinations)
    const int s_a = (lane < T) ? lane : lane - T;
    const int r_a = (lane < T) ? 0 : 1;
    const int dsta = r_a * GS + s_a;
    const int i2 = lane + 64;
    const int s_b = (i2 < 68) ? i2 - 34 : i2 - 68;
    const int r_b = (i2 < 68) ? 1 : 2;
    const int dstb = r_b * GS + s_b;
    const bool act2 = (i2 < 102);

    float* stg = stageAll + w * 896;
    float2* stg2 = reinterpret_cast<float2*>(stg);
    const f32x4* st4 = reinterpret_cast<const f32x4*>(stg);

    auto loadTok = [&](int p, int& t0A, int& t1A, int& toA, int& t0B, int& t1B, int& toB) {
        int tA = wid + (2 * p)     * NWAVES;
        int tB = wid + (2 * p + 1) * NWAVES;
        int bA = (tA * 64) / T, bB = (tB * 64) / T;
        t0A = idx[bA * T + lane];
        t1A = idx[min(bA * T + lane + 64, LIM - 1)];
        toA = idx[tA * 64 + lane];
        t0B = idx[bB * T + lane];
        t1B = idx[min(bB * T + lane + 64, LIM - 1)];
        toB = idx[tB * 64 + lane];
    };
    auto stageP = [&](float* dst, int t0A, int t1A, int t0B, int t1B) {
        dst[dsta] = G_lds[t0A * GS + s_a];
        if (act2) dst[dstb] = G_lds[t1A * GS + s_b];
        dst[112 + dsta] = G_lds[t0B * GS + s_a];
        if (act2) dst[112 + dstb] = G_lds[t1B * GS + s_b];
    };
    auto dot = [&](const float* gbT, int rbase) -> float {
        const f32x4* g4 = reinterpret_cast<const f32x4*>(gbT + rbase);
        float a0 = 0.f, a1 = 0.f;
        #pragma unroll
        for (int q = 0; q < 8; ++q) {
            f32x4 gg = g4[q];
            a0 = fmaf(A[4*q],   gg[0], a0);
            a1 = fmaf(A[4*q+1], gg[1], a1);
            a0 = fmaf(A[4*q+2], gg[2], a0);
            a1 = fmaf(A[4*q+3], gg[3], a1);
        }
        float2 tl = *reinterpret_cast<const float2*>(gbT + rbase + 32);
        a0 = fmaf(A[32], tl.x, a0);
        a1 = fmaf(A[33], tl.y, a1);
        return a0 + a1;
    };
    auto epiStore = [&](int tile, int curtok, float acc) {
        float2 te = *reinterpret_cast<const float2*>(&TE_lds[curtok * 2]);
        float x0 = te.x + acc * oB0;
        float x1 = te.y + acc * oB1;
        float x2 = ps0 + acc * oB2;
        float x3 = ps1 + acc * oB3;
        float x4 = ps2 + acc * oB4;

        float ms = (x0*x0 + x1*x1 + x2*x2 + x3*x3 + x4*x4) * 0.2f;
        float rr = rsqrtf(ms + 1e-5f);
        float h0 = x0*rr*nw0, h1 = x1*rr*nw1, h2 = x2*rr*nw2, h3 = x3*rr*nw3, h4 = x4*rr*nw4;
        float f0 = fmaxf(0.f, h0*w1[0][0] + h1*w1[0][1] + h2*w1[0][2] + h3*w1[0][3] + h4*w1[0][4]);
        float f1 = fmaxf(0.f, h0*w1[1][0] + h1*w1[1][1] + h2*w1[1][2] + h3*w1[1][3] + h4*w1[1][4]);
        x0 += f0*w20[0] + f1*w21[0];
        x1 += f0*w20[1] + f1*w21[1];
        x2 += f0*w20[2] + f1*w21[2];
        x3 += f0*w20[3] + f1*w21[3];
        x4 += f0*w20[4] + f1*w21[4];

        ms = (x0*x0 + x1*x1 + x2*x2 + x3*x3 + x4*x4) * 0.2f;
        rr = rsqrtf(ms + 1e-5f);
        h0 = x0*rr*nw0; h1 = x1*rr*nw1; h2 = x2*rr*nw2; h3 = x3*rr*nw3; h4 = x4*rr*nw4;
        float p0 = h0*hw[0][0] + h1*hw[0][1] + h2*hw[0][2] + h3*hw[0][3] + h4*hw[0][4];
        float p1 = h0*hw[1][0] + h1*hw[1][1] + h2*hw[1][2] + h3*hw[1][3] + h4*hw[1][4];

        #pragma unroll
        for (int j = 0; j < 7; ++j) {
            float2 o2;
            o2.x = p0 * te0[2*j]   + p1 * te1[2*j];
            o2.y = p0 * te0[2*j+1] + p1 * te1[2*j+1];
            stg2[lane * 7 + j] = o2;
        }
        // same-wave LDS ordering: reads below see the writes above
        f32x4* outp = reinterpret_cast<f32x4*>(out) + (size_t)tile * 224;
        __builtin_nontemporal_store(st4[lane],       outp + lane);
        __builtin_nontemporal_store(st4[lane + 64],  outp + lane + 64);
        __builtin_nontemporal_store(st4[lane + 128], outp + lane + 128);
        if (lane < 32)
            __builtin_nontemporal_store(st4[lane + 192], outp + lane + 192);
    };

    // ------------- main loop: 4 pairs; gb double-buffered one pair ahead -------------
    int c_toA, c_toB;
    int n_t0A, n_t1A, n_toA, n_t0B, n_t1B, n_toB;
    {
        int t0A, t1A, t0B, t1B;
        loadTok(0, t0A, t1A, c_toA, t0B, t1B, c_toB);
        stageP(&gbW[w][0][0][0], t0A, t1A, t0B, t1B);
    }
    loadTok(1, n_t0A, n_t1A, n_toA, n_t0B, n_t1B, n_toB);

    #pragma unroll
    for (int p = 0; p < NPAIRS; ++p) {
        const float* g = &gbW[w][p & 1][0][0];
        const int tA = wid + (2 * p)     * NWAVES;
        const int tB = wid + (2 * p + 1) * NWAVES;
        const int rbA = ((tA * 64 + lane) / T - (tA * 64) / T) * GS;
        const int rbB = ((tB * 64 + lane) / T - (tB * 64) / T) * GS;

        float accA = dot(g,       rbA);
        float accB = dot(g + 112, rbB);
        const int ctA = c_toA, ctB = c_toB;

        // stage next pair into alternate buffer (write->read latency hidden under epilogues)
        if (p < NPAIRS - 1) {
            stageP(&gbW[w][(p + 1) & 1][0][0], n_t0A, n_t1A, n_t0B, n_t1B);
            c_toA = n_toA; c_toB = n_toB;
            if (p < NPAIRS - 2)
                loadTok(p + 2, n_t0A, n_t1A, n_toA, n_t0B, n_t1B, n_toB);
        }

        epiStore(tA, ctA, accA);
        epiStore(tB, ctB, accB);
    }
}

extern "C" void kernel_launch(void* const* d_in, const int* in_sizes, int n_in,
                              void* d_out, int out_size, void* d_ws, size_t ws_size,
                              hipStream_t stream) {
    const int*   idx        = (const int*)  d_in[0];
    const float* tok_A      = (const float*)d_in[1];
    const float* tok_start  = (const float*)d_in[2];
    const float* tok_stride = (const float*)d_in[3];
    const float* sp_amp     = (const float*)d_in[4];
    const float* sp_phase   = (const float*)d_in[5];
    const float* sp_slope   = (const float*)d_in[6];
    const float* sp_offset  = (const float*)d_in[7];
    const float* norm_w     = (const float*)d_in[8];
    const float* q_w        = (const float*)d_in[9];
    const float* q_phase    = (const float*)d_in[10];
    const float* out_A      = (const float*)d_in[11];
    const float* out_B      = (const float*)d_in[12];
    const float* fc1_w      = (const float*)d_in[13];
    const float* fc2_w      = (const float*)d_in[14];
    const float* head_w     = (const float*)d_in[15];
    float* out = (float*)d_out;

    micro_fused<<<NBLK, NT, 0, stream>>>(idx, out, tok_A, tok_start, tok_stride,
                                         sp_amp, sp_phase, sp_slope, sp_offset,
                                         norm_w, q_w, q_phase, out_A, out_B,
                                         fc1_w, fc2_w, head_w);
}

// Round 15
// 40.757 us; speedup vs baseline: 2.0882x; 2.0882x over previous
//
#include <hip/hip_runtime.h>
#include <math.h>

#define T 34
#define V 14
#define NT 256
#define NBLK 2176
#define NWAVES 8704            // tile stride; 8704*32 % 34 == 0 -> per-lane t invariant
#define KTILES 8               // 8704*8 tiles * 32 items = 65536*34
#define LIM (65536 * 34)

typedef float f32x4 __attribute__((ext_vector_type(4)));

// ws layout (floats):
//   [0    .. 1224)  A_pad[34][36]  softmaxed causal attn row t; 0 for s>t and s>=34
//   [1224 .. 1728)  G_pad[14][36]  g(v,s), 0-padded
//   [1728 .. 1756)  TE pairs [14][2]
//   [1756 .. 1770)  te0[14]
//   [1770 .. 1784)  te1[14]
//   [1784 .. 1886)  POS[34][3]

__global__ void setup_k(const float* __restrict__ tokA_p, const float* __restrict__ tokStart_p,
                        const float* __restrict__ tokStride_p, const float* __restrict__ spAmp_p,
                        const float* __restrict__ spPhase_p, const float* __restrict__ spSlope_p,
                        const float* __restrict__ spOffset_p, const float* __restrict__ norm_w,
                        const float* __restrict__ q_w, const float* __restrict__ q_phase,
                        const float* __restrict__ out_A, float* __restrict__ ws)
{
    __shared__ float sPOS[T][3];
    __shared__ float sK[T][5];
    __shared__ float sQ[T][5];
    __shared__ float sTE[V][2];
    __shared__ float sA[T][35];

    const int tid = threadIdx.x;   // 64 threads, 1 block

    if (tid < V) {
        float ang = tokStart_p[0] + (float)tid * tokStride_p[0];
        float c = tokA_p[0] * cosf(ang), s = tokA_p[0] * sinf(ang);
        sTE[tid][0] = c; sTE[tid][1] = s;
        ws[1728 + 2 * tid] = c; ws[1729 + 2 * tid] = s;
        ws[1756 + tid] = c;      // te0
        ws[1770 + tid] = s;      // te1
    }
    if (tid < T) {
        float th = (float)tid * 0.62831853071795864769f + spPhase_p[0];
        float p0 = spAmp_p[0] * cosf(th), p1 = spAmp_p[0] * sinf(th);
        float p2 = spSlope_p[0] * (float)tid + spOffset_p[0];
        sPOS[tid][0] = p0; sPOS[tid][1] = p1; sPOS[tid][2] = p2;
        ws[1784 + 3 * tid] = p0; ws[1785 + 3 * tid] = p1; ws[1786 + 3 * tid] = p2;
        float kk[5];
        #pragma unroll
        for (int i = 0; i < 5; ++i)
            kk[i] = p0 * q_w[3 * i] + p1 * q_w[3 * i + 1] + p2 * q_w[3 * i + 2];
        float cc = cosf(q_phase[0]), ss = sinf(q_phase[0]);
        #pragma unroll
        for (int i = 0; i < 5; ++i) sK[tid][i] = kk[i];
        sQ[tid][0] = cc * kk[0] - ss * kk[1];
        sQ[tid][1] = ss * kk[0] + cc * kk[1];
        sQ[tid][2] = kk[2]; sQ[tid][3] = kk[3]; sQ[tid][4] = kk[4];
    }
    __syncthreads();

    if (tid < T) {
        const int t = tid;
        float mx = -1e30f;
        for (int s = 0; s <= t; ++s) {
            float d = (sQ[t][0] * sK[s][0] + sQ[t][1] * sK[s][1] + sQ[t][2] * sK[s][2]
                     + sQ[t][3] * sK[s][3] + sQ[t][4] * sK[s][4]) * 0.44721359549995793928f;
            sA[t][s] = d;
            mx = fmaxf(mx, d);
        }
        float sum = 0.f;
        for (int s = 0; s <= t; ++s) { float e = expf(sA[t][s] - mx); sA[t][s] = e; sum += e; }
        float inv = 1.f / sum;
        for (int s = 0; s < 36; ++s)
            ws[t * 36 + s] = (s <= t) ? sA[t][s] * inv : 0.f;
    }
    for (int e = tid; e < V * 36; e += 64) {
        int v = e / 36, s = e - v * 36;
        float g = 0.f;
        if (s < T) {
            float x0 = sTE[v][0], x1 = sTE[v][1];
            float x2 = sPOS[s][0], x3 = sPOS[s][1], x4 = sPOS[s][2];
            float ms = (x0*x0 + x1*x1 + x2*x2 + x3*x3 + x4*x4) * 0.2f;
            float r = rsqrtf(ms + 1e-5f);
            g = (x0 * norm_w[0] * out_A[0] + x1 * norm_w[1] * out_A[1]
               + x2 * norm_w[2] * out_A[2] + x3 * norm_w[3] * out_A[3]
               + x4 * norm_w[4] * out_A[4]) * r;
        }
        ws[1224 + e] = g;
    }
}

__global__ __launch_bounds__(NT) void micro_main(
    const int* __restrict__ idx, const float* __restrict__ ws, float* __restrict__ out,
    const float* __restrict__ norm_w, const float* __restrict__ out_B,
    const float* __restrict__ fc1_w, const float* __restrict__ fc2_w,
    const float* __restrict__ head_w)
{
    __shared__ float G_lds[V * 36];   // 2016 B
    __shared__ float TE_lds[V * 2];   // 112 B
    __shared__ float gbuf[4][72];     // per-wave staged g: 2 rows x 36 (slots 34,35 unused)
    __shared__ int   tokb[4][68];     // per-wave staged tokens
    __shared__ float stg[4][448];     // per-wave logit stage (32 items x 14)
    // total ~11.3 KB

    const int tid = threadIdx.x;
    const int w = tid >> 6, lane = tid & 63;
    const int li = lane & 31, hi = lane >> 5;
    const int wid = blockIdx.x * 4 + w;

    // one-time table load; the only barrier
    for (int i = tid; i < V * 36; i += NT) G_lds[i] = ws[1224 + i];
    if (tid < 28) TE_lds[tid] = ws[1728 + tid];
    __syncthreads();

    // ---- per-lane invariants ----
    const int t = (wid * 32 + li) % T;

    // A half-row: 18 floats from ws (L2-resident table). hi=0: s0..17 (zero 16,17); hi=1: s16..33
    const float* ap = ws + t * 36 + 16 * hi;
    const float4* ap4 = reinterpret_cast<const float4*>(ap);
    float4 Aa = ap4[0], Ab = ap4[1], Ac = ap4[2], Ad = ap4[3];
    float2 Ae = *reinterpret_cast<const float2*>(ap + 16);
    if (hi == 0) { Ae.x = 0.f; Ae.y = 0.f; }

    const float ps0 = ws[1784 + 3 * t], ps1 = ws[1785 + 3 * t], ps2 = ws[1786 + 3 * t];

    // wave-uniform weights: literal-indexed uniform loads -> SGPRs
    const float nw0 = norm_w[0], nw1 = norm_w[1], nw2 = norm_w[2], nw3 = norm_w[3], nw4 = norm_w[4];
    const float oB0 = out_B[0], oB1 = out_B[1], oB2 = out_B[2], oB3 = out_B[3], oB4 = out_B[4];
    const float w100 = fc1_w[0], w101 = fc1_w[1], w102 = fc1_w[2], w103 = fc1_w[3], w104 = fc1_w[4];
    const float w110 = fc1_w[5], w111 = fc1_w[6], w112 = fc1_w[7], w113 = fc1_w[8], w114 = fc1_w[9];
    const float hw00 = head_w[0], hw01 = head_w[1], hw02 = head_w[2], hw03 = head_w[3], hw04 = head_w[4];
    const float hw10 = head_w[5], hw11 = head_w[6], hw12 = head_w[7], hw13 = head_w[8], hw14 = head_w[9];
    const float w200 = fc2_w[0], w201 = fc2_w[1];
    const float w210 = fc2_w[2], w211 = fc2_w[3];
    const float w220 = fc2_w[4], w221 = fc2_w[5];
    const float w230 = fc2_w[6], w231 = fc2_w[7];
    const float w240 = fc2_w[8], w241 = fc2_w[9];

    // hi-selected te halves (14 VGPRs): lane writes logits v = 7*hi + m
    float t0s[7], t1s[7];
    #pragma unroll
    for (int m = 0; m < 7; ++m) {
        t0s[m] = hi ? ws[1756 + 7 + m] : ws[1756 + m];
        t1s[m] = hi ? ws[1770 + 7 + m] : ws[1770 + m];
    }

    int tile = wid;
    for (int k = 0; k < KTILES; ++k) {
        const int b0 = (int)((unsigned)(tile * 32) / 34u);
        const int base = b0 * T;

        // ---- stage 68 g values + tokens (2 rows) ----
        {
            int tk = idx[min(base + lane, LIM - 1)];
            int s = (lane < T) ? lane : lane - T;
            int slot = (lane < T) ? lane : lane + 2;   // row1 at offset 36
            gbuf[w][slot] = G_lds[tk * 36 + s];
            tokb[w][lane] = tk;
            if (lane < 4) {
                int j2 = 64 + lane;
                int tk2 = idx[min(base + j2, LIM - 1)];
                gbuf[w][j2 + 2] = G_lds[tk2 * 36 + (j2 - T)];
                tokb[w][j2] = tk2;
            }
        }

        const int j_own = tile * 32 + li - base;       // 0..67
        const int r = (j_own >= T) ? 1 : 0;

        // ---- half-dot (18 FMA) + cross-lane combine ----
        const float* gp = &gbuf[w][r * 36 + 16 * hi];
        const float4* gp4 = reinterpret_cast<const float4*>(gp);
        float4 g0 = gp4[0], g1 = gp4[1], g2 = gp4[2], g3 = gp4[3];
        float2 g4 = *reinterpret_cast<const float2*>(gp + 16);
        float a0 = 0.f, a1 = 0.f;
        a0 = fmaf(Aa.x, g0.x, a0); a1 = fmaf(Aa.y, g0.y, a1);
        a0 = fmaf(Aa.z, g0.z, a0); a1 = fmaf(Aa.w, g0.w, a1);
        a0 = fmaf(Ab.x, g1.x, a0); a1 = fmaf(Ab.y, g1.y, a1);
        a0 = fmaf(Ab.z, g1.z, a0); a1 = fmaf(Ab.w, g1.w, a1);
        a0 = fmaf(Ac.x, g2.x, a0); a1 = fmaf(Ac.y, g2.y, a1);
        a0 = fmaf(Ac.z, g2.z, a0); a1 = fmaf(Ac.w, g2.w, a1);
        a0 = fmaf(Ad.x, g3.x, a0); a1 = fmaf(Ad.y, g3.y, a1);
        a0 = fmaf(Ad.z, g3.z, a0); a1 = fmaf(Ad.w, g3.w, a1);
        a0 = fmaf(Ae.x, g4.x, a0); a1 = fmaf(Ae.y, g4.y, a1);
        float acc = a0 + a1;
        acc += __shfl_xor(acc, 32);

        // ---- epilogue (both lanes of the pair compute identically) ----
        int tok_own = tokb[w][j_own];
        float2 tet = *reinterpret_cast<const float2*>(&TE_lds[tok_own * 2]);
        float x0 = tet.x + acc * oB0;
        float x1 = tet.y + acc * oB1;
        float x2 = ps0 + acc * oB2;
        float x3 = ps1 + acc * oB3;
        float x4 = ps2 + acc * oB4;

        float ms = (x0*x0 + x1*x1 + x2*x2 + x3*x3 + x4*x4) * 0.2f;
        float rr = rsqrtf(ms + 1e-5f);
        float h0 = x0*rr*nw0, h1 = x1*rr*nw1, h2 = x2*rr*nw2, h3 = x3*rr*nw3, h4 = x4*rr*nw4;
        float f0 = fmaxf(0.f, h0*w100 + h1*w101 + h2*w102 + h3*w103 + h4*w104);
        float f1 = fmaxf(0.f, h0*w110 + h1*w111 + h2*w112 + h3*w113 + h4*w114);
        x0 += f0*w200 + f1*w201;
        x1 += f0*w210 + f1*w211;
        x2 += f0*w220 + f1*w221;
        x3 += f0*w230 + f1*w231;
        x4 += f0*w240 + f1*w241;

        ms = (x0*x0 + x1*x1 + x2*x2 + x3*x3 + x4*x4) * 0.2f;
        rr = rsqrtf(ms + 1e-5f);
        h0 = x0*rr*nw0; h1 = x1*rr*nw1; h2 = x2*rr*nw2; h3 = x3*rr*nw3; h4 = x4*rr*nw4;
        float p0 = h0*hw00 + h1*hw01 + h2*hw02 + h3*hw03 + h4*hw04;
        float p1 = h0*hw10 + h1*hw11 + h2*hw12 + h3*hw13 + h4*hw14;

        // ---- each lane writes its 7 logits (v = 7*hi + m) ----
        float* sp = &stg[w][li * 14 + 7 * hi];
        #pragma unroll
        for (int m = 0; m < 7; ++m)
            sp[m] = fmaf(p1, t1s[m], p0 * t0s[m]);

        // ---- coalesced copyout: 1792 B contiguous per tile ----
        const f32x4* s4 = reinterpret_cast<const f32x4*>(stg[w]);
        f32x4* op = reinterpret_cast<f32x4*>(out) + (size_t)tile * 112;
        __builtin_nontemporal_store(s4[lane], op + lane);
        if (lane < 48)
            __builtin_nontemporal_store(s4[64 + lane], op + 64 + lane);

        tile += NWAVES;
    }
}

extern "C" void kernel_launch(void* const* d_in, const int* in_sizes, int n_in,
                              void* d_out, int out_size, void* d_ws, size_t ws_size,
                              hipStream_t stream) {
    const int*   idx        = (const int*)  d_in[0];
    const float* tok_A      = (const float*)d_in[1];
    const float* tok_start  = (const float*)d_in[2];
    const float* tok_stride = (const float*)d_in[3];
    const float* sp_amp     = (const float*)d_in[4];
    const float* sp_phase   = (const float*)d_in[5];
    const float* sp_slope   = (const float*)d_in[6];
    const float* sp_offset  = (const float*)d_in[7];
    const float* norm_w     = (const float*)d_in[8];
    const float* q_w        = (const float*)d_in[9];
    const float* q_phase    = (const float*)d_in[10];
    const float* out_A      = (const float*)d_in[11];
    const float* out_B      = (const float*)d_in[12];
    const float* fc1_w      = (const float*)d_in[13];
    const float* fc2_w      = (const float*)d_in[14];
    const float* head_w     = (const float*)d_in[15];
    float* out = (float*)d_out;
    float* ws  = (float*)d_ws;

    setup_k<<<1, 64, 0, stream>>>(tok_A, tok_start, tok_stride, sp_amp, sp_phase,
                                  sp_slope, sp_offset, norm_w, q_w, q_phase, out_A, ws);
    micro_main<<<NBLK, NT, 0, stream>>>(idx, ws, out, norm_w, out_B, fc1_w, fc2_w, head_w);
}